// Round 2
// baseline (415.624 us; speedup 1.0000x reference)
//
#include <hip/hip_runtime.h>
#include <hip/hip_bf16.h>

#define HH 96
#define WW 96
#define NPIX 9216          // H*W
#define DDIM 1152          // 128*9
#define NKT 36             // K tiles of 32 (1152/32)
#define BM 256
#define BN 128
#define MT 36              // NPIX/BM
#define NT 72              // NPIX/BN
#define NBLK (MT * NT)     // 2592, %8 == 0
#define TOTAL_ELEMS 1179648

typedef float f32x4 __attribute__((ext_vector_type(4)));
typedef __bf16 bf16x8 __attribute__((ext_vector_type(8)));

__device__ __forceinline__ void gload_lds16(const void* g, void* l) {
  __builtin_amdgcn_global_load_lds((const __attribute__((address_space(1))) void*)g,
                                   (__attribute__((address_space(3))) void*)l, 16, 0, 0);
}

// Build patch matrix P[n][d], d = c*9 + (ki*3+kj). blockIdx.y: 0 = style (+rnorm), 1 = content.
__global__ void build_patches_kernel(const float* __restrict__ style_f,
                                     const float* __restrict__ content_f,
                                     __hip_bfloat16* __restrict__ Ps,
                                     __hip_bfloat16* __restrict__ Pc,
                                     float* __restrict__ rnorm) {
  const int n = blockIdx.x;        // pixel
  const int c = threadIdx.x;       // channel (128 threads)
  const bool is_style = (blockIdx.y == 0);
  const float* f = is_style ? style_f : content_f;
  __hip_bfloat16* P = is_style ? Ps : Pc;
  const int y = n / WW, x = n % WW;
  const float* fc = f + (size_t)c * NPIX;
  float vals[9];
  float ss = 0.f;
#pragma unroll
  for (int ki = 0; ki < 3; ++ki) {
    int yy = y + ki - 1;
#pragma unroll
    for (int kj = 0; kj < 3; ++kj) {
      int xx = x + kj - 1;
      float v = (yy >= 0 && yy < HH && xx >= 0 && xx < WW) ? fc[yy * WW + xx] : 0.f;
      vals[ki * 3 + kj] = v;
      ss += v * v;
    }
  }
  __hip_bfloat16* dst = P + (size_t)n * DDIM + c * 9;
#pragma unroll
  for (int t = 0; t < 9; ++t) dst[t] = __float2bfloat16(vals[t]);
  if (is_style) {
    __shared__ float red[128];
    red[c] = ss;
    __syncthreads();
#pragma unroll
    for (int s = 64; s > 0; s >>= 1) {
      if (c < s) red[c] += red[c + s];
      __syncthreads();
    }
    if (c == 0) rnorm[n] = 1.0f / fmaxf(sqrtf(red[0]), 1e-12f);
  }
}

// Fused GEMM + argmax. Block: 256 rows x 128 styles, 4 waves (2M x 2N), wave tile 128x64.
// BK=32 double-buffered (48 KB LDS -> 2 blocks/CU), counted-vmcnt pipeline (T4),
// raw s_barrier, setprio around MFMA cluster (T5). Per-row best via 64-bit key atomicMax.
__global__ __launch_bounds__(256, 2)
void gemm_argmax_kernel(const __hip_bfloat16* __restrict__ Pc,
                        const __hip_bfloat16* __restrict__ Ps,
                        const float* __restrict__ rnorm,
                        unsigned long long* __restrict__ keytab) {
  __shared__ int4 smem4[3072];  // 48 KB: 2 bufs x (A 16KB + B 8KB)
  char* smem = (char*)smem4;
  const int tid = threadIdx.x;
  const int lane = tid & 63;
  const int wid = tid >> 6;
  const int l15 = lane & 15;
  const int lg = lane >> 4;
  const int wm = wid >> 1;     // 0..1 (M half)
  const int wn = wid & 1;      // 0..1 (N half)

  // XCD-aware bijective swizzle (NBLK % 8 == 0)
  const int orig = blockIdx.x;
  const int swz = (orig & 7) * (NBLK / 8) + (orig >> 3);
  const int mt = swz / NT;
  const int nt = swz - mt * NT;
  const int bm0 = mt * BM;
  const int sbase = nt * BN;

  // staging map: thread -> (row = tid/4, slot = tid%3..), k-group pre-swizzled
  const int srow = tid >> 2;                       // 0..63 rows per round
  const int sg = (tid & 3) ^ (srow & 3);           // inverse-swizzled source k-slot
  const __hip_bfloat16* pa = Pc + (size_t)(bm0 + srow) * DDIM + sg * 8;
  const __hip_bfloat16* pb = Ps + (size_t)(sbase + srow) * DDIM + sg * 8;
  const int sdst = tid * 16;                       // linear LDS dest (wave-uniform base + lane*16)

  auto stage = [&](int buf, int kt) {
    char* la = smem + buf * 24576 + sdst;
    const int ko = kt * 32;
#pragma unroll
    for (int i = 0; i < 4; ++i)  // A: 256 rows, 64/round
      gload_lds16(pa + (size_t)i * 64 * DDIM + ko, la + i * 4096);
#pragma unroll
    for (int j = 0; j < 2; ++j)  // B: 128 rows
      gload_lds16(pb + (size_t)j * 64 * DDIM + ko, la + 16384 + j * 4096);
  };

  // fragment read byte offsets (swizzled): row*64 + ((lg ^ (row&3))<<4)
  const int sx = (lg ^ (l15 & 3)) << 4;
  int aoff[8], boff[4];
#pragma unroll
  for (int mf = 0; mf < 8; ++mf)
    aoff[mf] = (wm * 128 + mf * 16 + l15) * 64 + sx;
#pragma unroll
  for (int nf = 0; nf < 4; ++nf)
    boff[nf] = 16384 + (wn * 64 + nf * 16 + l15) * 64 + sx;

  f32x4 acc[8][4];
#pragma unroll
  for (int mf = 0; mf < 8; ++mf)
#pragma unroll
    for (int nf = 0; nf < 4; ++nf) {
      f32x4 z = {0.f, 0.f, 0.f, 0.f};
      acc[mf][nf] = z;
    }

  auto compute = [&](int buf) {
    const char* bp = smem + buf * 24576;
    bf16x8 af[8], bfr[4];
#pragma unroll
    for (int mf = 0; mf < 8; ++mf)
      af[mf] = __builtin_bit_cast(bf16x8, *(const int4*)(bp + aoff[mf]));
#pragma unroll
    for (int nf = 0; nf < 4; ++nf)
      bfr[nf] = __builtin_bit_cast(bf16x8, *(const int4*)(bp + boff[nf]));
    __builtin_amdgcn_s_setprio(1);
#pragma unroll
    for (int mf = 0; mf < 8; ++mf)
#pragma unroll
      for (int nf = 0; nf < 4; ++nf)
        acc[mf][nf] = __builtin_amdgcn_mfma_f32_16x16x32_bf16(af[mf], bfr[nf], acc[mf][nf], 0, 0, 0);
    __builtin_amdgcn_s_setprio(0);
  };

  stage(0, 0);
  int cur = 0;
  for (int kt = 0; kt < NKT - 1; ++kt) {
    stage(cur ^ 1, kt + 1);                       // prefetch next K-tile (6 loads in flight)
    asm volatile("s_waitcnt vmcnt(6)" ::: "memory");  // wait ONLY buf[cur]'s loads
    __builtin_amdgcn_s_barrier();                 // all waves: buf[cur] staged
    __builtin_amdgcn_sched_barrier(0);            // no read hoisting above barrier
    compute(cur);
    __builtin_amdgcn_s_barrier();                 // reads of buf[cur] consumed before overwrite
    cur ^= 1;
  }
  asm volatile("s_waitcnt vmcnt(0)" ::: "memory");
  __builtin_amdgcn_s_barrier();
  __builtin_amdgcn_sched_barrier(0);
  compute(cur);

  // Epilogue: per-row argmax over this block's 128 cols -> global atomicMax on 64-bit key.
  float rn[4];
#pragma unroll
  for (int nf = 0; nf < 4; ++nf) rn[nf] = rnorm[sbase + wn * 64 + nf * 16 + l15];
#pragma unroll
  for (int mf = 0; mf < 8; ++mf)
#pragma unroll
    for (int r = 0; r < 4; ++r) {
      float v = -3.0e38f;
      int bi = 0;
#pragma unroll
      for (int nf = 0; nf < 4; ++nf) {            // ascending cols: strict > keeps first max
        float x = acc[mf][nf][r] * rn[nf];
        int col = sbase + wn * 64 + nf * 16 + l15;
        if (x > v) { v = x; bi = col; }
      }
#pragma unroll
      for (int m = 1; m < 16; m <<= 1) {          // reduce over l15 (16 cols/lane-group)
        float ov = __shfl_xor(v, m, 64);
        int oi = __shfl_xor(bi, m, 64);
        if (ov > v || (ov == v && oi < bi)) { v = ov; bi = oi; }
      }
      if (l15 == 0) {
        int row = bm0 + wm * 128 + mf * 16 + lg * 4 + r;
        unsigned u = __float_as_uint(v);
        u ^= (unsigned)((int)u >> 31) | 0x80000000u;   // monotone float->uint
        unsigned long long key =
            ((unsigned long long)u << 32) | (unsigned)(0xFFFFFFFFu ^ (unsigned)bi);
        atomicMax(keytab + row, key);             // ties -> smaller col wins
      }
    }
}

__global__ void recon_mse_kernel(const float* __restrict__ content,
                                 const float* __restrict__ style,
                                 const unsigned long long* __restrict__ keytab,
                                 float* __restrict__ out) {
  int idx = blockIdx.x * 256 + threadIdx.x;
  float sq = 0.f;
  if (idx < TOTAL_ELEMS) {
    int c = idx / NPIX;
    int pix = idx - c * NPIX;
    int y = pix / WW, x = pix - (pix / WW) * WW;
    float sum = 0.f, cnt = 0.f;
#pragma unroll
    for (int ki = 0; ki < 3; ++ki) {
      int yn = y - ki + 1;
      if (yn < 0 || yn >= HH) continue;
#pragma unroll
      for (int kj = 0; kj < 3; ++kj) {
        int xn = x - kj + 1;
        if (xn < 0 || xn >= WW) continue;
        cnt += 1.f;
        int m = (int)(0xFFFFFFFFu ^ (unsigned)(keytab[yn * WW + xn] & 0xFFFFFFFFull));
        int ys = m / WW, xs = m - (m / WW) * WW;
        int sy = ys + ki - 1, sx = xs + kj - 1;
        if (sy >= 0 && sy < HH && sx >= 0 && sx < WW)
          sum += style[(size_t)c * NPIX + sy * WW + sx];
      }
    }
    float recon = sum / (cnt + 1e-8f);
    float d = content[idx] - recon;
    sq = d * d;
  }
#pragma unroll
  for (int m = 32; m > 0; m >>= 1) sq += __shfl_down(sq, m, 64);
  __shared__ float wsum[4];
  int lane = threadIdx.x & 63, w = threadIdx.x >> 6;
  if (lane == 0) wsum[w] = sq;
  __syncthreads();
  if (threadIdx.x == 0) {
    float t = wsum[0] + wsum[1] + wsum[2] + wsum[3];
    atomicAdd(out, t * (1.0f / (float)TOTAL_ELEMS));
  }
}

extern "C" void kernel_launch(void* const* d_in, const int* in_sizes, int n_in,
                              void* d_out, int out_size, void* d_ws, size_t ws_size,
                              hipStream_t stream) {
  const float* content = (const float*)d_in[0];
  const float* stylef = (const float*)d_in[1];
  float* out = (float*)d_out;
  char* ws = (char*)d_ws;

  const size_t PS_OFF = 0;
  const size_t PC_OFF = (size_t)NPIX * DDIM * 2;     // 21,233,664
  const size_t RN_OFF = PC_OFF * 2;                  // 42,467,328
  const size_t KEY_OFF = RN_OFF + (size_t)NPIX * 4;  // 42,504,192

  __hip_bfloat16* Ps = (__hip_bfloat16*)(ws + PS_OFF);
  __hip_bfloat16* Pc = (__hip_bfloat16*)(ws + PC_OFF);
  float* rnorm = (float*)(ws + RN_OFF);
  unsigned long long* keytab = (unsigned long long*)(ws + KEY_OFF);

  hipMemsetAsync(d_out, 0, (size_t)out_size * sizeof(float), stream);
  hipMemsetAsync(keytab, 0, (size_t)NPIX * 8, stream);
  build_patches_kernel<<<dim3(NPIX, 2), 128, 0, stream>>>(stylef, content, Ps, Pc, rnorm);
  gemm_argmax_kernel<<<NBLK, 256, 0, stream>>>(Pc, Ps, rnorm, keytab);
  recon_mse_kernel<<<TOTAL_ELEMS / 256, 256, 0, stream>>>(content, stylef, keytab, out);
}

// Round 3
// 362.814 us; speedup vs baseline: 1.1456x; 1.1456x over previous
//
#include <hip/hip_runtime.h>
#include <hip/hip_bf16.h>

#define HH 96
#define WW 96
#define NPIX 9216          // H*W
#define DDIM 1152          // 128*9
#define NKT 36             // K tiles of 32 (1152/32)
#define BM 256
#define BN 128
#define MT 36              // NPIX/BM
#define NT 72              // NPIX/BN
#define NBLK (MT * NT)     // 2592, %8 == 0
#define TOTAL_ELEMS 1179648
#define CG 32              // channels per build group

typedef float f32x4 __attribute__((ext_vector_type(4)));
typedef __bf16 bf16x8 __attribute__((ext_vector_type(8)));

__device__ __forceinline__ void gload_lds16(const void* g, void* l) {
  __builtin_amdgcn_global_load_lds((const __attribute__((address_space(1))) void*)g,
                                   (__attribute__((address_space(3))) void*)l, 16, 0, 0);
}

// Patch builder: block = (row y, channel-group cg, src). LDS-staged coalesced reads,
// 16B vector writes of P rows; also emits style_T [pix][c] f32 when requested.
__global__ __launch_bounds__(256)
void build_patches_kernel(const float* __restrict__ style_f,
                          const float* __restrict__ content_f,
                          __bf16* __restrict__ Ps, __bf16* __restrict__ Pc,
                          float* __restrict__ styT) {
  __shared__ float ftile[CG][3][104];  // padded: stride 312 breaks bank alignment
  const int y = blockIdx.x;            // 0..95
  const int cg = blockIdx.y;           // 0..3
  const bool is_style = (blockIdx.z == 0);
  const float* f = is_style ? style_f : content_f;
  __bf16* P = is_style ? Ps : Pc;
  const int tid = threadIdx.x;

  for (int i = tid; i < CG * 3 * 96; i += 256) {
    int cl = i / 288, rem = i - cl * 288;
    int yy = rem / 96, xx = rem - yy * 96;
    int gy = y + yy - 1;
    float v = (gy >= 0 && gy < HH) ? f[(size_t)(cg * CG + cl) * NPIX + gy * WW + xx] : 0.f;
    ftile[cl][yy][xx] = v;
  }
  __syncthreads();

  if (is_style && styT != nullptr) {
    for (int i = tid; i < 96 * CG; i += 256) {
      int px = i / CG, cl = i - px * CG;
      styT[(size_t)(y * WW + px) * 128 + cg * CG + cl] = ftile[cl][1][px];
    }
  }

  for (int j = tid; j < 96 * 36; j += 256) {  // 36 vec8 chunks per pixel (this c-group)
    int px = j / 36, wi = j - px * 36;
    bf16x8 tmp;
#pragma unroll
    for (int u = 0; u < 8; ++u) {
      int e = wi * 8 + u;                 // 0..287 within group
      int cl = e / 9, t = e - cl * 9;
      int ki = t / 3, kj = t - ki * 3;
      int xx = px + kj - 1;
      float v = (xx >= 0 && xx < WW) ? ftile[cl][ki][xx] : 0.f;
      tmp[u] = (__bf16)v;
    }
    *(bf16x8*)(P + (size_t)(y * WW + px) * DDIM + cg * 288 + wi * 8) = tmp;
  }
}

// Deterministic per-pixel style norms from Ps rows (one wave per pixel).
__global__ __launch_bounds__(256)
void norm_kernel(const __bf16* __restrict__ Ps, float* __restrict__ rnorm) {
  const int n = blockIdx.x * 4 + (threadIdx.x >> 6);
  const int lane = threadIdx.x & 63;
  const bf16x8* row = (const bf16x8*)(Ps + (size_t)n * DDIM);  // 144 vec8
  float ss = 0.f;
#pragma unroll
  for (int i = 0; i < 3; ++i) {
    int idx = i * 64 + lane;
    if (idx < 144) {
      bf16x8 v = row[idx];
#pragma unroll
      for (int u = 0; u < 8; ++u) { float x = (float)v[u]; ss += x * x; }
    }
  }
#pragma unroll
  for (int m = 1; m < 64; m <<= 1) ss += __shfl_xor(ss, m, 64);
  if (lane == 0) rnorm[n] = 1.0f / fmaxf(sqrtf(ss), 1e-12f);
}

// Fused GEMM + argmax. 256x128 tile, 4 waves (2Mx2N), wave tile 128x64.
// BK=32 TRIPLE-buffered (72 KB LDS), depth-2 counted vmcnt(12), raw barriers,
// conflict-free (row>>1)&3 slot swizzle (round-1 scheme, 0 conflicts).
__global__ __launch_bounds__(256, 2)
void gemm_argmax_kernel(const __bf16* __restrict__ Pc,
                        const __bf16* __restrict__ Ps,
                        const float* __restrict__ rnorm,
                        unsigned long long* __restrict__ keytab) {
  __shared__ int4 smem4[4608];  // 72 KB: 3 bufs x (A 16KB + B 8KB)
  char* smem = (char*)smem4;
  const int tid = threadIdx.x;
  const int lane = tid & 63;
  const int wid = tid >> 6;
  const int l15 = lane & 15;
  const int lg = lane >> 4;
  const int wm = wid >> 1;
  const int wn = wid & 1;

  const int orig = blockIdx.x;
  const int swz = (orig & 7) * (NBLK / 8) + (orig >> 3);
  const int mt = swz / NT;
  const int nt = swz - mt * NT;
  const int bm0 = mt * BM;
  const int sbase = nt * BN;

  // staging: row = tid/4, slot = tid%3.. ; source k-group = slot ^ ((row>>1)&3)
  const int srow = tid >> 2;
  const int sg = (tid & 3) ^ ((srow >> 1) & 3);
  const __bf16* pa = Pc + (size_t)(bm0 + srow) * DDIM + sg * 8;
  const __bf16* pb = Ps + (size_t)(sbase + srow) * DDIM + sg * 8;
  const int sdst = tid * 16;

  auto stage = [&](int buf, int kt) {
    char* la = smem + buf * 24576 + sdst;
    const int ko = kt * 32;
#pragma unroll
    for (int i = 0; i < 4; ++i)
      gload_lds16(pa + (size_t)i * 64 * DDIM + ko, la + i * 4096);
#pragma unroll
    for (int j = 0; j < 2; ++j)
      gload_lds16(pb + (size_t)j * 64 * DDIM + ko, la + 16384 + j * 4096);
  };

  // reads: row r slot (lg ^ ((r>>1)&3)); for r = 16a + l15, (r>>1)&3 == (l15>>1)&3
  const int sx = (lg ^ ((l15 >> 1) & 3)) << 4;
  int aoff[8], boff[4];
#pragma unroll
  for (int mf = 0; mf < 8; ++mf)
    aoff[mf] = (wm * 128 + mf * 16 + l15) * 64 + sx;
#pragma unroll
  for (int nf = 0; nf < 4; ++nf)
    boff[nf] = 16384 + (wn * 64 + nf * 16 + l15) * 64 + sx;

  f32x4 acc[8][4];
#pragma unroll
  for (int mf = 0; mf < 8; ++mf)
#pragma unroll
    for (int nf = 0; nf < 4; ++nf) {
      f32x4 z = {0.f, 0.f, 0.f, 0.f};
      acc[mf][nf] = z;
    }

  auto compute = [&](int buf) {
    const char* bp = smem + buf * 24576;
    bf16x8 af[8], bfr[4];
#pragma unroll
    for (int mf = 0; mf < 8; ++mf)
      af[mf] = __builtin_bit_cast(bf16x8, *(const int4*)(bp + aoff[mf]));
#pragma unroll
    for (int nf = 0; nf < 4; ++nf)
      bfr[nf] = __builtin_bit_cast(bf16x8, *(const int4*)(bp + boff[nf]));
    __builtin_amdgcn_s_setprio(1);
#pragma unroll
    for (int mf = 0; mf < 8; ++mf)
#pragma unroll
      for (int nf = 0; nf < 4; ++nf)
        acc[mf][nf] = __builtin_amdgcn_mfma_f32_16x16x32_bf16(af[mf], bfr[nf], acc[mf][nf], 0, 0, 0);
    __builtin_amdgcn_s_setprio(0);
  };

  stage(0, 0);
  stage(1, 1);
  int sb = 2, cb = 0;
  for (int kt = 0; kt < NKT - 2; ++kt) {
    stage(sb, kt + 2);                  // issue 6 loads (depth-2 ahead)
    sb = (sb == 2) ? 0 : sb + 1;
    asm volatile("s_waitcnt vmcnt(12)" ::: "memory");  // drain ONLY tile kt's 6
    __builtin_amdgcn_s_barrier();
    __builtin_amdgcn_sched_barrier(0);
    compute(cb);
    __builtin_amdgcn_s_barrier();       // readers done before buf[cb] restaged next iter
    cb = (cb == 2) ? 0 : cb + 1;
  }
  asm volatile("s_waitcnt vmcnt(6)" ::: "memory");
  __builtin_amdgcn_s_barrier();
  __builtin_amdgcn_sched_barrier(0);
  compute(cb);
  cb = (cb == 2) ? 0 : cb + 1;
  asm volatile("s_waitcnt vmcnt(0)" ::: "memory");
  __builtin_amdgcn_s_barrier();
  __builtin_amdgcn_sched_barrier(0);
  compute(cb);

  // per-row argmax over this block's 128 cols -> 64-bit monotone-key atomicMax
  float rn[4];
#pragma unroll
  for (int nf = 0; nf < 4; ++nf) rn[nf] = rnorm[sbase + wn * 64 + nf * 16 + l15];
#pragma unroll
  for (int mf = 0; mf < 8; ++mf)
#pragma unroll
    for (int r = 0; r < 4; ++r) {
      float v = -3.0e38f;
      int bi = 0;
#pragma unroll
      for (int nf = 0; nf < 4; ++nf) {
        float x = acc[mf][nf][r] * rn[nf];
        int col = sbase + wn * 64 + nf * 16 + l15;
        if (x > v) { v = x; bi = col; }
      }
#pragma unroll
      for (int m = 1; m < 16; m <<= 1) {
        float ov = __shfl_xor(v, m, 64);
        int oi = __shfl_xor(bi, m, 64);
        if (ov > v || (ov == v && oi < bi)) { v = ov; bi = oi; }
      }
      if (l15 == 0) {
        int row = bm0 + wm * 128 + mf * 16 + lg * 4 + r;
        unsigned u = __float_as_uint(v);
        u ^= (unsigned)((int)u >> 31) | 0x80000000u;
        unsigned long long key =
            ((unsigned long long)u << 32) | (unsigned)(0xFFFFFFFFu ^ (unsigned)bi);
        atomicMax(keytab + row, key);
      }
    }
}

// Recon+MSE: block = 2 pixels x 128 channels. TMODE: style from styT (coalesced over c);
// else gather bf16 taps straight from Ps (zero padding baked into P rows).
// Content from Pc center tap (bf16).
template <bool TMODE>
__global__ __launch_bounds__(256)
void recon_mse_kernel(const __bf16* __restrict__ Pc, const __bf16* __restrict__ Ps,
                      const float* __restrict__ styT,
                      const unsigned long long* __restrict__ keytab,
                      float* __restrict__ out) {
  const int pix = blockIdx.x * 2 + (threadIdx.x >> 7);
  const int c = threadIdx.x & 127;
  const int y = pix / WW, x = pix - (pix / WW) * WW;
  float sum = 0.f, cnt = 0.f;
#pragma unroll
  for (int ki = 0; ki < 3; ++ki) {
    int yn = y - ki + 1;
    if (yn < 0 || yn >= HH) continue;
#pragma unroll
    for (int kj = 0; kj < 3; ++kj) {
      int xn = x - kj + 1;
      if (xn < 0 || xn >= WW) continue;
      cnt += 1.f;
      int m = (int)(0xFFFFFFFFu ^ (unsigned)(keytab[yn * WW + xn] & 0xFFFFFFFFull));
      if (TMODE) {
        int ys = m / WW, xs = m - (m / WW) * WW;
        int sy = ys + ki - 1, sx = xs + kj - 1;
        if (sy >= 0 && sy < HH && sx >= 0 && sx < WW)
          sum += styT[(size_t)(sy * WW + sx) * 128 + c];
      } else {
        sum += (float)Ps[(size_t)m * DDIM + c * 9 + ki * 3 + kj];
      }
    }
  }
  float recon = sum / (cnt + 1e-8f);
  float cv = (float)Pc[(size_t)pix * DDIM + c * 9 + 4];  // center tap == content value
  float d = cv - recon;
  float sq = d * d;
#pragma unroll
  for (int m = 32; m > 0; m >>= 1) sq += __shfl_down(sq, m, 64);
  __shared__ float wsum[4];
  int lane = threadIdx.x & 63, w = threadIdx.x >> 6;
  if (lane == 0) wsum[w] = sq;
  __syncthreads();
  if (threadIdx.x == 0)
    atomicAdd(out, (wsum[0] + wsum[1] + wsum[2] + wsum[3]) * (1.0f / (float)TOTAL_ELEMS));
}

extern "C" void kernel_launch(void* const* d_in, const int* in_sizes, int n_in,
                              void* d_out, int out_size, void* d_ws, size_t ws_size,
                              hipStream_t stream) {
  const float* content = (const float*)d_in[0];
  const float* stylef = (const float*)d_in[1];
  float* out = (float*)d_out;
  char* ws = (char*)d_ws;

  const size_t PS_OFF = 0;
  const size_t PC_OFF = (size_t)NPIX * DDIM * 2;       // 21,233,664
  const size_t RN_OFF = PC_OFF * 2;                    // 42,467,328
  const size_t KEY_OFF = RN_OFF + (size_t)NPIX * 4;    // 42,504,192
  const size_t ST_OFF = KEY_OFF + (size_t)NPIX * 8;    // 42,577,920
  const size_t END_T = ST_OFF + (size_t)NPIX * 128 * 4;  // 47,296,512

  __bf16* Ps = (__bf16*)(ws + PS_OFF);
  __bf16* Pc = (__bf16*)(ws + PC_OFF);
  float* rnorm = (float*)(ws + RN_OFF);
  unsigned long long* keytab = (unsigned long long*)(ws + KEY_OFF);
  const bool tmode = ws_size >= END_T;
  float* styT = tmode ? (float*)(ws + ST_OFF) : nullptr;

  hipMemsetAsync(d_out, 0, (size_t)out_size * sizeof(float), stream);
  hipMemsetAsync(keytab, 0, (size_t)NPIX * 8, stream);
  build_patches_kernel<<<dim3(96, 4, 2), 256, 0, stream>>>(stylef, content, Ps, Pc, styT);
  norm_kernel<<<NPIX / 4, 256, 0, stream>>>(Ps, rnorm);
  gemm_argmax_kernel<<<NBLK, 256, 0, stream>>>(Pc, Ps, rnorm, keytab);
  if (tmode)
    recon_mse_kernel<true><<<NPIX / 2, 256, 0, stream>>>(Pc, Ps, styT, keytab, out);
  else
    recon_mse_kernel<false><<<NPIX / 2, 256, 0, stream>>>(Pc, Ps, nullptr, keytab, out);
}